// Round 9
// baseline (183.778 us; speedup 1.0000x reference)
//
#include <hip/hip_runtime.h>
#include <hip/hip_bf16.h>
#include <stdint.h>

#define B_ROWS 16384
#define NVARS 64
#define LAG 16
#define H1 64
#define H2 1024
#define KDIM (NVARS * H1)   // 4096

typedef __attribute__((ext_vector_type(8))) short short8;
typedef __attribute__((ext_vector_type(4))) short short4v;
typedef __attribute__((ext_vector_type(4))) float f32x4;

typedef __attribute__((address_space(3))) uint8_t lds_u8;
typedef const __attribute__((address_space(1))) uint8_t glob_u8;

__device__ __forceinline__ void gload_lds16(const void* g, void* l) {
    __builtin_amdgcn_global_load_lds((glob_u8*)g, (lds_u8*)l, 16, 0, 0);
}

__device__ __forceinline__ short f2bf_s(float x) {
    __hip_bfloat16 h = __float2bfloat16(x);
    return *(short*)&h;
}
__device__ __forceinline__ float bf_s2f(short s) {
    __hip_bfloat16 h = *(__hip_bfloat16*)&s;
    return __bfloat162float(h);
}

// ---------------------------------------------------------------------------
// Kernel 1 (run-once misc, one dispatch): W3 transpose / out init / W1,W2 prep
// ---------------------------------------------------------------------------
__global__ __launch_bounds__(256) void misc_pre_kernel(
    const float* __restrict__ w3, const float* __restrict__ b4,
    const float* __restrict__ W1, const float* __restrict__ W2,
    __hip_bfloat16* __restrict__ w3t, float* __restrict__ out,
    short* __restrict__ w1bh, short* __restrict__ w1bl,
    short* __restrict__ w2bh, short* __restrict__ w2bl) {
    __shared__ float tile[64][65];
    const int bid = blockIdx.x;
    const int t = threadIdx.x;

    if (bid < 1024) {
        const int k0 = (bid >> 4) * 64;
        const int n0 = (bid & 15) * 64;
        const int c = t & 63, r0 = t >> 6;
#pragma unroll
        for (int i = 0; i < 16; i++) {
            int r = r0 + i * 4;
            tile[r][c] = w3[(size_t)(k0 + r) * H2 + n0 + c];
        }
        __syncthreads();
#pragma unroll
        for (int i = 0; i < 16; i++) {
            int nr = r0 + i * 4;
            w3t[(size_t)(n0 + nr) * KDIM + k0 + c] = __float2bfloat16(tile[c][nr]);
        }
        return;
    }
    if (bid < 1088) {
        out[(bid - 1024) * 256 + t] = b4[0];
        return;
    }

    const int v = bid - 1088;
    for (int idx = t; idx < 64 * 32; idx += 256) {
        int col = idx >> 5, k = idx & 31;
        float wv = W1[((size_t)v * LAG + (k & 15)) * H1 + col];
        short hi = f2bf_s(wv);
        w1bh[((size_t)v * 64 + col) * 40 + k] = hi;
        w1bl[((size_t)v * 64 + col) * 40 + k] = (k < 16) ? f2bf_s(wv - bf_s2f(hi)) : (short)0;
    }
    for (int idx = t; idx < 64 * 64; idx += 256) {
        int col = idx >> 6, k = idx & 63;
        float wv = W2[((size_t)v * H1 + k) * H1 + col];
        short hi = f2bf_s(wv);
        w2bh[((size_t)v * 64 + col) * 72 + k] = hi;
        w2bl[((size_t)v * 64 + col) * 72 + k] = f2bf_s(wv - bf_s2f(hi));
    }
}

// ---------------------------------------------------------------------------
// Kernel 2: per-variable 2-layer subnet via split-bf16 MFMA (r8-validated).
// ---------------------------------------------------------------------------
__global__ __launch_bounds__(256) void subnets_mfma_kernel(
    const float* __restrict__ inputs, const float* __restrict__ b1g,
    const float* __restrict__ b2g, const float* __restrict__ impg,
    const short* __restrict__ w1bh_g, const short* __restrict__ w1bl_g,
    const short* __restrict__ w2bh_g, const short* __restrict__ w2bl_g,
    __hip_bfloat16* __restrict__ agg) {
    const int v = blockIdx.x >> 7;
    const int b0 = (blockIdx.x & 127) * 128;
    const int t = threadIdx.x;
    const int lane = t & 63, wv = t >> 6;
    const int l15 = lane & 15, g = lane >> 4;

    __shared__ __align__(16) char smem[38912];
    short* xsS   = (short*)smem;
    short* w1bhS = (short*)(smem + 10240);
    short* w1blS = (short*)(smem + 15360);
    short* Hs    = (short*)smem;
    short* w2bhS = (short*)(smem + 20480);
    short* w2blS = (short*)(smem + 29696);

    for (int c = t; c < 320; c += 256) {
        gload_lds16(w1bh_g + (size_t)v * 2560 + c * 8, (char*)w1bhS + c * 16);
        gload_lds16(w1bl_g + (size_t)v * 2560 + c * 8, (char*)w1blS + c * 16);
    }
    for (int c = t; c < 576; c += 256) {
        gload_lds16(w2bh_g + (size_t)v * 4608 + c * 8, (char*)w2bhS + c * 16);
        gload_lds16(w2bl_g + (size_t)v * 4608 + c * 8, (char*)w2blS + c * 16);
    }
#pragma unroll
    for (int i = 0; i < 2; i++) {
        int idx = t + i * 256;
        int row = idx >> 2, seg = idx & 3;
        float4 x4 = *(const float4*)(inputs + (size_t)(b0 + row) * (NVARS * LAG) + v * LAG + seg * 4);
        const float* xp = (const float*)&x4;
        short4v hv, lv;
#pragma unroll
        for (int j = 0; j < 4; j++) {
            short hi = f2bf_s(xp[j]);
            hv[j] = hi;
            lv[j] = f2bf_s(xp[j] - bf_s2f(hi));
        }
        *(short4v*)&xsS[row * 40 + seg * 4] = hv;
        *(short4v*)&xsS[row * 40 + 16 + seg * 4] = lv;
    }
    __syncthreads();

    short8 a1[2], b1hF[4], b1lF[4];
#pragma unroll
    for (int mt = 0; mt < 2; mt++)
        a1[mt] = *(const short8*)&xsS[(wv * 32 + mt * 16 + l15) * 40 + g * 8];
#pragma unroll
    for (int nt = 0; nt < 4; nt++) {
        b1hF[nt] = *(const short8*)&w1bhS[(nt * 16 + l15) * 40 + g * 8];
        b1lF[nt] = *(const short8*)&w1blS[(nt * 16 + l15) * 40 + g * 8];
    }
    f32x4 acc1[2][4];
#pragma unroll
    for (int mt = 0; mt < 2; mt++)
#pragma unroll
        for (int nt = 0; nt < 4; nt++) {
            acc1[mt][nt] = (f32x4){0.f, 0.f, 0.f, 0.f};
            acc1[mt][nt] = __builtin_amdgcn_mfma_f32_16x16x32_bf16(a1[mt], b1hF[nt], acc1[mt][nt], 0, 0, 0);
            acc1[mt][nt] = __builtin_amdgcn_mfma_f32_16x16x32_bf16(a1[mt], b1lF[nt], acc1[mt][nt], 0, 0, 0);
        }
    __syncthreads();

#pragma unroll
    for (int mt = 0; mt < 2; mt++)
#pragma unroll
        for (int nt = 0; nt < 4; nt++) {
            int col = nt * 16 + l15;
            float bias = b1g[v * H1 + col];
#pragma unroll
            for (int r = 0; r < 4; r++) {
                float h = fmaxf(acc1[mt][nt][r] + bias, 0.f);
                int row = wv * 32 + mt * 16 + g * 4 + r;
                Hs[row * 72 + col] = f2bf_s(h);
            }
        }
    __syncthreads();

    short8 a2[2][2], b2hF[4][2], b2lF[4][2];
#pragma unroll
    for (int mt = 0; mt < 2; mt++)
#pragma unroll
        for (int kc = 0; kc < 2; kc++)
            a2[mt][kc] = *(const short8*)&Hs[(wv * 32 + mt * 16 + l15) * 72 + kc * 32 + g * 8];
#pragma unroll
    for (int nt = 0; nt < 4; nt++)
#pragma unroll
        for (int kc = 0; kc < 2; kc++) {
            b2hF[nt][kc] = *(const short8*)&w2bhS[(nt * 16 + l15) * 72 + kc * 32 + g * 8];
            b2lF[nt][kc] = *(const short8*)&w2blS[(nt * 16 + l15) * 72 + kc * 32 + g * 8];
        }
    f32x4 acc2[2][4];
#pragma unroll
    for (int mt = 0; mt < 2; mt++)
#pragma unroll
        for (int nt = 0; nt < 4; nt++) {
            f32x4 a = (f32x4){0.f, 0.f, 0.f, 0.f};
            a = __builtin_amdgcn_mfma_f32_16x16x32_bf16(a2[mt][0], b2hF[nt][0], a, 0, 0, 0);
            a = __builtin_amdgcn_mfma_f32_16x16x32_bf16(a2[mt][1], b2hF[nt][1], a, 0, 0, 0);
            a = __builtin_amdgcn_mfma_f32_16x16x32_bf16(a2[mt][0], b2lF[nt][0], a, 0, 0, 0);
            a = __builtin_amdgcn_mfma_f32_16x16x32_bf16(a2[mt][1], b2lF[nt][1], a, 0, 0, 0);
            acc2[mt][nt] = a;
        }

    const float impv = impg[v];
#pragma unroll
    for (int mt = 0; mt < 2; mt++)
#pragma unroll
        for (int nt = 0; nt < 4; nt++) {
            int col = nt * 16 + l15;
            float bias = b2g[v * H1 + col];
#pragma unroll
            for (int r = 0; r < 4; r++) {
                float o = fmaxf(acc2[mt][nt][r] + bias, 0.f) * impv;
                int row = b0 + wv * 32 + mt * 16 + g * 4 + r;
                agg[(size_t)row * KDIM + v * H1 + col] = __float2bfloat16(o);
            }
        }
}

// ---------------------------------------------------------------------------
// Kernel 3: relu(agg @ W3 + b3) . W4 -> atomicAdd into out.
// r9: cross-tile register-fragment prefetch. Per tile tt:
//   { 12 ds_reads of tile tt+1's frags (alt reg set, buf (tt+1)&3) |
//     stage tile tt+3 | 32 MFMA on CURRENT regs (no lgkmcnt dep!) |
//     vmcnt(4) (certifies tt+1,tt+2 staged) | barrier }
// Ledger: prefetch of tt+1 at tile tt is safe because end-of-(tt-1)'s
// vmcnt(4) left only tt+2's stage outstanding. Buf overwrite (tt+3)&3 is
// 2 barriers after that buf's last ds_read. Named reg sets (rule #20).
// ---------------------------------------------------------------------------
#define NT 128   // K-tiles of 32

__global__ __launch_bounds__(512, 2) void gemm3_kernel(
    const __hip_bfloat16* __restrict__ agg,   // [16384][4096]
    const __hip_bfloat16* __restrict__ w3t,   // [1024][4096]
    const float* __restrict__ b3, const float* __restrict__ W4,
    float* __restrict__ out) {
    const int bid = ((blockIdx.x & 7) << 5) + (blockIdx.x >> 3);
    const int brow = (bid >> 2) * 256;
    const int bcol = (bid & 3) * 256;
    const int t = threadIdx.x;
    const int lane = t & 63;
    const int wid = t >> 6;
    const int wm = wid >> 2, wn = wid & 3;
    const int l15 = lane & 15, g = lane >> 4;

    __shared__ __align__(16) char smem[131072];

    const int c0 = t, c1 = t + 512;
    const int r0 = c0 >> 2, r1 = c1 >> 2;
    const int col0 = ((c0 & 3) * 8) ^ ((r0 & 8) ? 16 : 0);
    const int col1 = ((c1 & 3) * 8) ^ ((r1 & 8) ? 16 : 0);
    const __hip_bfloat16* aS0 = agg + (size_t)(brow + r0) * KDIM + col0;
    const __hip_bfloat16* aS1 = agg + (size_t)(brow + r1) * KDIM + col1;
    const __hip_bfloat16* bS0 = w3t + (size_t)(bcol + r0) * KDIM + col0;
    const __hip_bfloat16* bS1 = w3t + (size_t)(bcol + r1) * KDIM + col1;

#define STAGE_AB(p, kt) do { \
        gload_lds16(aS0 + (kt) * 32, smem + (p) * 32768 + c0 * 16); \
        gload_lds16(aS1 + (kt) * 32, smem + (p) * 32768 + c1 * 16); \
        gload_lds16(bS0 + (kt) * 32, smem + (p) * 32768 + 16384 + c0 * 16); \
        gload_lds16(bS1 + (kt) * 32, smem + (p) * 32768 + 16384 + c1 * 16); } while (0)

    const int coff = (g * 16) ^ ((l15 & 8) ? 32 : 0);
    const int aBase = (wm * 128 + l15) * 64 + coff;
    const int bBase = 16384 + (wn * 64 + l15) * 64 + coff;

#define RD(p, off) (*(const short8*)(smem + (p) * 32768 + (off)))
#define LDFRAGS(FA, FB, p) do { \
        FA[0] = RD(p, aBase + 0 * 1024); FA[1] = RD(p, aBase + 1 * 1024); \
        FA[2] = RD(p, aBase + 2 * 1024); FA[3] = RD(p, aBase + 3 * 1024); \
        FA[4] = RD(p, aBase + 4 * 1024); FA[5] = RD(p, aBase + 5 * 1024); \
        FA[6] = RD(p, aBase + 6 * 1024); FA[7] = RD(p, aBase + 7 * 1024); \
        FB[0] = RD(p, bBase + 0 * 1024); FB[1] = RD(p, bBase + 1 * 1024); \
        FB[2] = RD(p, bBase + 2 * 1024); FB[3] = RD(p, bBase + 3 * 1024); } while (0)

#define MM(FA, FB) do { \
        __builtin_amdgcn_s_setprio(1); \
        _Pragma("unroll") \
        for (int mm = 0; mm < 8; mm++) \
            _Pragma("unroll") \
            for (int nn = 0; nn < 4; nn++) \
                acc[mm][nn] = __builtin_amdgcn_mfma_f32_16x16x32_bf16( \
                    FA[mm], FB[nn], acc[mm][nn], 0, 0, 0); \
        __builtin_amdgcn_s_setprio(0); } while (0)

#define TILE(FAc, FBc, FAn, FBn, tn, DOPREF, DOSTAGE, kt3, VMSTR) do { \
        if (DOPREF) LDFRAGS(FAn, FBn, (tn) & 3); \
        if (DOSTAGE) STAGE_AB((kt3) & 3, kt3); \
        MM(FAc, FBc); \
        asm volatile(VMSTR ::: "memory"); \
        __builtin_amdgcn_s_barrier(); \
        __builtin_amdgcn_sched_barrier(0); } while (0)

    short8 fa0[8], fb0[4], fa1[8], fb1[4];
    f32x4 acc[8][4];
#pragma unroll
    for (int m = 0; m < 8; m++)
#pragma unroll
        for (int n = 0; n < 4; n++) acc[m][n] = (f32x4){0.f, 0.f, 0.f, 0.f};

    // prologue: stage tiles 0,1,2 (12 gloads); vmcnt(4) certifies 0,1;
    // barrier; read tile0 frags into set0.
    STAGE_AB(0, 0);
    STAGE_AB(1, 1);
    STAGE_AB(2, 2);
    asm volatile("s_waitcnt vmcnt(4)" ::: "memory");
    __builtin_amdgcn_s_barrier();
    __builtin_amdgcn_sched_barrier(0);
    LDFRAGS(fa0, fb0, 0);

    // main loop: tt = 0..123; even tt -> cur set0, odd -> cur set1
#pragma unroll 4
    for (int tt = 0; tt < NT - 4; ++tt) {
        if (tt & 1) TILE(fa1, fb1, fa0, fb0, tt + 1, 1, 1, tt + 3, "s_waitcnt vmcnt(4)");
        else        TILE(fa0, fb0, fa1, fb1, tt + 1, 1, 1, tt + 3, "s_waitcnt vmcnt(4)");
    }
    // tail: 124 (stages 127), 125, 126, 127
    TILE(fa0, fb0, fa1, fb1, 125, 1, 1, 127, "s_waitcnt vmcnt(4)");
    TILE(fa1, fb1, fa0, fb0, 126, 1, 0, 0,   "s_waitcnt vmcnt(0)");
    TILE(fa0, fb0, fa1, fb1, 127, 1, 0, 0,   "s_waitcnt vmcnt(0)");
    MM(fa1, fb1);   // tile 127, no prefetch/stage/barrier

    // epilogue: bias+relu, dot W4, 16-lane reduce, atomicAdd per row
    float bias[4], w4v[4];
#pragma unroll
    for (int n = 0; n < 4; n++) {
        int col = bcol + wn * 64 + n * 16 + l15;
        bias[n] = b3[col];
        w4v[n] = W4[col];
    }
#pragma unroll
    for (int m = 0; m < 8; m++) {
        float pr0 = 0.f, pr1 = 0.f, pr2 = 0.f, pr3 = 0.f;
#pragma unroll
        for (int n = 0; n < 4; n++) {
            pr0 += fmaxf(acc[m][n][0] + bias[n], 0.f) * w4v[n];
            pr1 += fmaxf(acc[m][n][1] + bias[n], 0.f) * w4v[n];
            pr2 += fmaxf(acc[m][n][2] + bias[n], 0.f) * w4v[n];
            pr3 += fmaxf(acc[m][n][3] + bias[n], 0.f) * w4v[n];
        }
#pragma unroll
        for (int mask = 1; mask < 16; mask <<= 1) {
            pr0 += __shfl_xor(pr0, mask, 64);
            pr1 += __shfl_xor(pr1, mask, 64);
            pr2 += __shfl_xor(pr2, mask, 64);
            pr3 += __shfl_xor(pr3, mask, 64);
        }
        if (l15 == 0) {
            int row = brow + wm * 128 + m * 16 + g * 4;
            atomicAdd(&out[row + 0], pr0);
            atomicAdd(&out[row + 1], pr1);
            atomicAdd(&out[row + 2], pr2);
            atomicAdd(&out[row + 3], pr3);
        }
    }
}

// ---------------------------------------------------------------------------
extern "C" void kernel_launch(void* const* d_in, const int* in_sizes, int n_in,
                              void* d_out, int out_size, void* d_ws, size_t ws_size,
                              hipStream_t stream) {
    const float* inputs = (const float*)d_in[0];
    const float* W1 = (const float*)d_in[1];
    const float* b1 = (const float*)d_in[2];
    const float* W2 = (const float*)d_in[3];
    const float* b2 = (const float*)d_in[4];
    const float* imp = (const float*)d_in[5];
    const float* W3 = (const float*)d_in[6];
    const float* b3 = (const float*)d_in[7];
    const float* W4 = (const float*)d_in[8];
    const float* b4 = (const float*)d_in[9];
    float* out = (float*)d_out;

    char* ws = (char*)d_ws;
    const size_t agg_bytes = (size_t)B_ROWS * KDIM * 2;        // 134 MB
    const size_t w3t_bytes = (size_t)H2 * KDIM * 2;            // 8.4 MB
    const size_t w1b_bytes = (size_t)NVARS * 64 * 40 * 2;
    const size_t w2b_bytes = (size_t)NVARS * 64 * 72 * 2;

    __hip_bfloat16* agg = (__hip_bfloat16*)ws;
    __hip_bfloat16* w3t = (__hip_bfloat16*)(ws + agg_bytes);
    short* w1bh = (short*)(ws + agg_bytes + w3t_bytes);
    short* w1bl = (short*)(ws + agg_bytes + w3t_bytes + w1b_bytes);
    short* w2bh = (short*)(ws + agg_bytes + w3t_bytes + 2 * w1b_bytes);
    short* w2bl = (short*)(ws + agg_bytes + w3t_bytes + 2 * w1b_bytes + w2b_bytes);

    hipLaunchKernelGGL(misc_pre_kernel, dim3(1152), dim3(256), 0, stream,
                       W3, b4, W1, W2, w3t, out, w1bh, w1bl, w2bh, w2bl);
    hipLaunchKernelGGL(subnets_mfma_kernel, dim3(NVARS * (B_ROWS / 128)), dim3(256), 0, stream,
                       inputs, b1, b2, imp, w1bh, w1bl, w2bh, w2bl, agg);
    hipLaunchKernelGGL(gemm3_kernel, dim3((B_ROWS / 256) * (H2 / 256)), dim3(512), 0, stream,
                       agg, w3t, b3, W4, out);
}